// Round 9
// baseline (146.385 us; speedup 1.0000x reference)
//
#include <hip/hip_runtime.h>
#include <hip/hip_bf16.h>

// Problem constants
#define N_ROWS 8192
#define F_DIM  512
#define D_DIM  64
#define C_CODES 8192

typedef __attribute__((ext_vector_type(8))) short bf16x8;   // 8 bf16 = 4 VGPRs
typedef __attribute__((ext_vector_type(4))) float f32x4;

__device__ __forceinline__ unsigned short rne_bf16(float x) {
  unsigned u = __float_as_uint(x);
  return (unsigned short)((u + 0x7FFFu + ((u >> 16) & 1u)) >> 16);
}
__device__ __forceinline__ float bf16_to_f(unsigned short u) {
  return __uint_as_float(((unsigned)u) << 16);
}
// split 8 floats into 3 bf16 limbs (h+m+l reproduces x to ~2^-24 rel)
__device__ __forceinline__ void limb3(const float* xs, bf16x8& H, bf16x8& M, bf16x8& L) {
  #pragma unroll
  for (int j = 0; j < 8; ++j) {
    float x = xs[j];
    unsigned short h = rne_bf16(x);
    float r1 = x - bf16_to_f(h);
    unsigned short m = rne_bf16(r1);
    float r2 = r1 - bf16_to_f(m);
    unsigned short lo = rne_bf16(r2);
    H[j] = (short)h; M[j] = (short)m; L[j] = (short)lo;
  }
}

// async global->LDS, 16B per lane; LDS dest is wave-uniform base + lane*16
typedef __attribute__((address_space(1))) const unsigned char gas_uchar;
typedef __attribute__((address_space(3))) unsigned char las_uchar;
__device__ __forceinline__ void gld_lds16(const void* g, void* l) {
  __builtin_amdgcn_global_load_lds((gas_uchar*)g, (las_uchar*)l, 16, 0, 0);
}

// ---------------------------------------------------------------------------
// K0: fused prep — W_in swizzle (blocks 0..15), W_out swizzle (16..31),
// codebook normalize + frag emit (32..159). Also zero-inits the loss output
// (k_out atomically accumulates into it; stream order guarantees init-first).
__global__ __launch_bounds__(256) void k_prep(
    const float* __restrict__ W_in, const float* __restrict__ W_out,
    const float* __restrict__ cb,
    unsigned short* __restrict__ win_sw, unsigned short* __restrict__ wout_sw,
    float* __restrict__ cn, unsigned short* __restrict__ cn_sw,
    float* __restrict__ loss_f) {
  const int tid = threadIdx.x, w = tid >> 6, l = tid & 63;
  const int lo = l & 15, hi = l >> 4;
  const int bid = blockIdx.x;
  if (bid == 0 && tid == 0) loss_f[0] = 0.0f;

  if (bid < 16) {
    // W_in [512][64] -> frags ((kc*4+cg)*3+m)*512 + l*8 + j
    const int task = bid * 4 + w;           // 0..63
    const int kc = task >> 2, cg = task & 3;
    float xs[8];
    #pragma unroll
    for (int j = 0; j < 8; ++j)
      xs[j] = W_in[(size_t)(kc * 32 + hi * 8 + j) * D_DIM + cg * 16 + lo];
    bf16x8 H, M, L;
    limb3(xs, H, M, L);
    const int fb = (kc * 4 + cg) * 3;
    unsigned short* d0 = win_sw + (size_t)(fb + 0) * 512 + l * 8;
    *(bf16x8*)d0 = H;
    *(bf16x8*)(d0 + 512) = M;
    *(bf16x8*)(d0 + 1024) = L;
  } else if (bid < 32) {
    // W_out [64][512] -> frags ((cg*2+c)*3+m)*512 + l*8 + j
    const int task = (bid - 16) * 4 + w;    // 0..63
    const int cg = task >> 1, c = task & 1;
    float xs[8];
    #pragma unroll
    for (int j = 0; j < 8; ++j)
      xs[j] = W_out[(size_t)(c * 32 + hi * 8 + j) * F_DIM + cg * 16 + lo];
    bf16x8 H, M, L;
    limb3(xs, H, M, L);
    const int fb = (cg * 2 + c) * 3;
    unsigned short* d0 = wout_sw + (size_t)(fb + 0) * 512 + l * 8;
    *(bf16x8*)d0 = H;
    *(bf16x8*)(d0 + 512) = M;
    *(bf16x8*)(d0 + 1024) = L;
  } else {
    // cn = normalise(codebook): fp32 rows + 3-limb frags
    const int g = (bid - 32) * 4 + w;       // 0..511
    const int code = g * 16 + lo;
    float xs[2][8];
    float s = 0.0f;
    #pragma unroll
    for (int c = 0; c < 2; ++c) {
      const float* sp = cb + (size_t)code * D_DIM + c * 32 + hi * 8;
      float4 a = *(const float4*)sp, b = *(const float4*)(sp + 4);
      xs[c][0]=a.x; xs[c][1]=a.y; xs[c][2]=a.z; xs[c][3]=a.w;
      xs[c][4]=b.x; xs[c][5]=b.y; xs[c][6]=b.z; xs[c][7]=b.w;
      #pragma unroll
      for (int j = 0; j < 8; ++j) s += xs[c][j] * xs[c][j];
    }
    s += __shfl_xor(s, 16);
    s += __shfl_xor(s, 32);
    float inv = rsqrtf(s * (1.0f / 64.0f) + 1e-12f);
    #pragma unroll
    for (int c = 0; c < 2; ++c) {
      #pragma unroll
      for (int j = 0; j < 8; ++j) xs[c][j] *= inv;
      float* dp = cn + (size_t)code * D_DIM + c * 32 + hi * 8;
      *(float4*)dp = make_float4(xs[c][0], xs[c][1], xs[c][2], xs[c][3]);
      *(float4*)(dp + 4) = make_float4(xs[c][4], xs[c][5], xs[c][6], xs[c][7]);
      bf16x8 H, M, L;
      limb3(xs[c], H, M, L);
      const int fb = (g * 2 + c) * 3;
      unsigned short* d0 = cn_sw + (size_t)(fb + 0) * 512 + l * 8;
      *(bf16x8*)d0 = H;
      *(bf16x8*)(d0 + 512) = M;
      *(bf16x8*)(d0 + 1024) = L;
    }
  }
}

// ---------------------------------------------------------------------------
// K1 v4 (R2-proven): zn = normalise(z @ W_in + b_in). 512 blocks x 4 waves:
// K=512 split as 128 per wave (4 kc-chunks), LDS cross-wave reduce,
// per-wave normalize. Direct global z loads + register B ping-pong.
__global__ __launch_bounds__(256) void k_zn(
    const float* __restrict__ z, const unsigned short* __restrict__ w_in_sw,
    const float* __restrict__ b_in, float* __restrict__ zn,
    unsigned short* __restrict__ zn_sw) {
  __shared__ float red[4096];        // [w][cg][r][lane] scalar layout
  __shared__ float t_lds[16 * 65];
  const int tid = threadIdx.x, w = tid >> 6, l = tid & 63;
  const int lo = l & 15, hi = l >> 4;
  const int g = blockIdx.x;          // 16-row group
  const int r0 = g * 16;
  const int kcb = w * 4;             // this wave's K-quarter (4 kc-chunks)
  const bf16x8* Bptr = (const bf16x8*)w_in_sw;
  const float* zbase = z + (size_t)(r0 + lo) * F_DIM + hi * 8;

  f32x4 acc[4];
  #pragma unroll
  for (int cg = 0; cg < 4; ++cg) acc[cg] = (f32x4){0.f, 0.f, 0.f, 0.f};

  bf16x8 Bu[12], Bv[12];
  #pragma unroll
  for (int i = 0; i < 12; ++i) Bu[i] = Bptr[((size_t)kcb * 12 + i) * 64 + l];
  float4 za = *(const float4*)(zbase + kcb * 32);
  float4 zb = *(const float4*)(zbase + kcb * 32 + 4);

  #define ZMFMA(BCUR)                                                         \
    {                                                                         \
      float xs[8] = {za.x, za.y, za.z, za.w, zb.x, zb.y, zb.z, zb.w};         \
      bf16x8 Ah, Am, Al;                                                      \
      limb3(xs, Ah, Am, Al);                                                  \
      _Pragma("unroll")                                                       \
      for (int cg = 0; cg < 4; ++cg) {                                        \
        f32x4 t = acc[cg];                                                    \
        t = __builtin_amdgcn_mfma_f32_16x16x32_bf16(Ah, BCUR[cg*3+0], t, 0,0,0); \
        t = __builtin_amdgcn_mfma_f32_16x16x32_bf16(Ah, BCUR[cg*3+1], t, 0,0,0); \
        t = __builtin_amdgcn_mfma_f32_16x16x32_bf16(Am, BCUR[cg*3+0], t, 0,0,0); \
        t = __builtin_amdgcn_mfma_f32_16x16x32_bf16(Ah, BCUR[cg*3+2], t, 0,0,0); \
        t = __builtin_amdgcn_mfma_f32_16x16x32_bf16(Al, BCUR[cg*3+0], t, 0,0,0); \
        t = __builtin_amdgcn_mfma_f32_16x16x32_bf16(Am, BCUR[cg*3+1], t, 0,0,0); \
        acc[cg] = t;                                                          \
      }                                                                       \
    }

  {  // step 0: compute kcb, prefetch kcb+1 into Bv
    float4 na = *(const float4*)(zbase + (kcb + 1) * 32);
    float4 nb = *(const float4*)(zbase + (kcb + 1) * 32 + 4);
    #pragma unroll
    for (int i = 0; i < 12; ++i) Bv[i] = Bptr[((size_t)(kcb + 1) * 12 + i) * 64 + l];
    ZMFMA(Bu)
    za = na; zb = nb;
  }
  {  // step 1
    float4 na = *(const float4*)(zbase + (kcb + 2) * 32);
    float4 nb = *(const float4*)(zbase + (kcb + 2) * 32 + 4);
    #pragma unroll
    for (int i = 0; i < 12; ++i) Bu[i] = Bptr[((size_t)(kcb + 2) * 12 + i) * 64 + l];
    ZMFMA(Bv)
    za = na; zb = nb;
  }
  {  // step 2
    float4 na = *(const float4*)(zbase + (kcb + 3) * 32);
    float4 nb = *(const float4*)(zbase + (kcb + 3) * 32 + 4);
    #pragma unroll
    for (int i = 0; i < 12; ++i) Bv[i] = Bptr[((size_t)(kcb + 3) * 12 + i) * 64 + l];
    ZMFMA(Bu)
    za = na; zb = nb;
  }
  ZMFMA(Bv)   // step 3: no prefetch
  #undef ZMFMA

  // cross-wave K reduction (conflict-free scalar layout, stride-1 lanes)
  #pragma unroll
  for (int cg = 0; cg < 4; ++cg)
    #pragma unroll
    for (int r = 0; r < 4; ++r)
      red[((w * 4 + cg) * 4 + r) * 64 + l] = acc[cg][r];
  __syncthreads();

  // wave w normalizes output rows hi*4 + w
  {
    float v[4], s = 0.0f;
    #pragma unroll
    for (int cg = 0; cg < 4; ++cg) {
      float t = b_in[cg * 16 + lo];
      #pragma unroll
      for (int w2 = 0; w2 < 4; ++w2) t += red[((w2 * 4 + cg) * 4 + w) * 64 + l];
      v[cg] = t; s += t * t;
    }
    s += __shfl_xor(s, 1);
    s += __shfl_xor(s, 2);
    s += __shfl_xor(s, 4);
    s += __shfl_xor(s, 8);
    float inv = rsqrtf(s * (1.0f / 64.0f) + 1e-12f);
    #pragma unroll
    for (int cg = 0; cg < 4; ++cg)
      t_lds[(hi * 4 + w) * 65 + cg * 16 + lo] = v[cg] * inv;
  }
  __syncthreads();

  // waves 0,1 emit fp32 + frags (A-frag order: row = lo, ks = c*32+hi*8+j)
  if (w < 2) {
    const int c = w;
    float xs[8];
    #pragma unroll
    for (int j = 0; j < 8; ++j) xs[j] = t_lds[lo * 65 + c * 32 + hi * 8 + j];
    float* dp = zn + (size_t)(r0 + lo) * D_DIM + c * 32 + hi * 8;
    *(float4*)dp = make_float4(xs[0], xs[1], xs[2], xs[3]);
    *(float4*)(dp + 4) = make_float4(xs[4], xs[5], xs[6], xs[7]);
    bf16x8 H, M, L;
    limb3(xs, H, M, L);
    const int fb = (g * 2 + c) * 3;
    unsigned short* d0 = zn_sw + (size_t)(fb + 0) * 512 + l * 8;
    *(bf16x8*)d0 = H;
    *(bf16x8*)(d0 + 512) = M;
    *(bf16x8*)(d0 + 1024) = L;
  }
}

// ---------------------------------------------------------------------------
// K3 v6 (R2-proven, 48.7us): 16x16x32 MFMA argmax, LDS-staged B shared by
// the block's 4 waves, 2 groups (12KB) per step double-buffered. Single
// dispatch restored (R8's diagnostic split cost +4us and served its purpose).
__global__ __launch_bounds__(256) void k_argmax(
    const unsigned short* __restrict__ zn_sw,
    const unsigned short* __restrict__ cn_sw,
    float* __restrict__ pval, int* __restrict__ pidx) {
  __shared__ short smem[2 * 12 * 512];        // 2 bufs x 12 frags x 1KB
  const int tid = threadIdx.x;
  const int w = tid >> 6, l = tid & 63;
  const int lo = l & 15, hi = l >> 4;
  const int gA0 = (blockIdx.x * 4 + w) * 2;   // 0..510 (16-row groups)
  const int gB0 = blockIdx.y * 32;            // B group base (32 groups/slice)
  const bf16x8* Ab = (const bf16x8*)zn_sw;
  const char* Bbytes = (const char*)cn_sw;

  bf16x8 A0[2][3], A1[2][3];
  #pragma unroll
  for (int c = 0; c < 2; ++c)
    #pragma unroll
    for (int m = 0; m < 3; ++m) {
      A0[c][m] = Ab[(size_t)((gA0 * 2 + c) * 3 + m) * 64 + l];
      A1[c][m] = Ab[(size_t)(((gA0 + 1) * 2 + c) * 3 + m) * 64 + l];
    }

  float bv[8];
  int bi[8];
  #pragma unroll
  for (int i = 0; i < 8; ++i) { bv[i] = -1e30f; bi[i] = 0; }
  int cand = blockIdx.y * 512 + lo;

  // stage step s (2 groups = 12 contiguous 1KB frags) into buffer b;
  // wave w copies frags w*3 .. w*3+2. LDS dest is wave-uniform.
  #define STAGE(b, s)                                                         \
    {                                                                         \
      const int fb = (gB0 + (s) * 2) * 6 + w * 3;                             \
      _Pragma("unroll")                                                       \
      for (int i = 0; i < 3; ++i)                                             \
        gld_lds16(Bbytes + ((size_t)(fb + i) << 10) + (size_t)l * 16,         \
                  &smem[((b) * 12 + w * 3 + i) * 512]);                       \
    }

  #define MF(A_, B_, C_) __builtin_amdgcn_mfma_f32_16x16x32_bf16(A_, B_, C_, 0, 0, 0)

  // one 16-code group: B frags at local frag base LF (c*3+m layout)
  #define COMPUTE(LF)                                                         \
    {                                                                         \
      bf16x8 Bf[6];                                                           \
      _Pragma("unroll")                                                       \
      for (int i = 0; i < 6; ++i)                                             \
        Bf[i] = *(const bf16x8*)&smem[((LF) + i) * 512 + l * 8];              \
      f32x4 a0 = {0.f,0.f,0.f,0.f}, a1 = {0.f,0.f,0.f,0.f};                   \
      f32x4 a2 = {0.f,0.f,0.f,0.f}, a3 = {0.f,0.f,0.f,0.f};                   \
      a0 = MF(A0[0][0], Bf[0], a0); a1 = MF(A0[1][0], Bf[3], a1);             \
      a2 = MF(A1[0][0], Bf[0], a2); a3 = MF(A1[1][0], Bf[3], a3);             \
      a0 = MF(A0[0][0], Bf[1], a0); a1 = MF(A0[1][0], Bf[4], a1);             \
      a2 = MF(A1[0][0], Bf[1], a2); a3 = MF(A1[1][0], Bf[4], a3);             \
      a0 = MF(A0[0][1], Bf[0], a0); a1 = MF(A0[1][1], Bf[3], a1);             \
      a2 = MF(A1[0][1], Bf[0], a2); a3 = MF(A1[1][1], Bf[3], a3);             \
      a0 = MF(A0[0][0], Bf[2], a0); a1 = MF(A0[1][0], Bf[5], a1);             \
      a2 = MF(A1[0][0], Bf[2], a2); a3 = MF(A1[1][0], Bf[5], a3);             \
      a0 = MF(A0[0][2], Bf[0], a0); a1 = MF(A0[1][2], Bf[3], a1);             \
      a2 = MF(A1[0][2], Bf[0], a2); a3 = MF(A1[1][2], Bf[3], a3);             \
      a0 = MF(A0[0][1], Bf[1], a0); a1 = MF(A0[1][1], Bf[4], a1);             \
      a2 = MF(A1[0][1], Bf[1], a2); a3 = MF(A1[1][1], Bf[4], a3);             \
      _Pragma("unroll")                                                       \
      for (int r = 0; r < 4; ++r) {                                           \
        float d0 = a0[r] + a1[r];                                             \
        if (d0 > bv[r]) { bv[r] = d0; bi[r] = cand; }                         \
        float d1 = a2[r] + a3[r];                                             \
        if (d1 > bv[4 + r]) { bv[4 + r] = d1; bi[4 + r] = cand; }             \
      }                                                                       \
      cand += 16;                                                             \
    }

  STAGE(0, 0)
  __syncthreads();
  int cur = 0;
  for (int s = 0; s < 16; ++s) {
    if (s < 15) STAGE(cur ^ 1, s + 1)
    COMPUTE(cur * 12 + 0)
    COMPUTE(cur * 12 + 6)
    __syncthreads();      // drains stage loads; protects buffer reuse
    cur ^= 1;
  }
  #undef STAGE
  #undef COMPUTE
  #undef MF

  #pragma unroll
  for (int i = 0; i < 8; ++i) {
    float v = bv[i]; int ix = bi[i];
    #pragma unroll
    for (int m = 1; m < 16; m <<= 1) {
      float ov = __shfl_xor(v, m);
      int oi = __shfl_xor(ix, m);
      if (ov > v || (ov == v && oi < ix)) { v = ov; ix = oi; }
    }
    bv[i] = v; bi[i] = ix;
  }
  if (lo == 0) {
    int off = blockIdx.y * N_ROWS;
    int base0 = gA0 * 16 + hi * 4;
    int base1 = (gA0 + 1) * 16 + hi * 4;
    #pragma unroll
    for (int r = 0; r < 4; ++r) {
      pval[off + base0 + r] = bv[r];     pidx[off + base0 + r] = bi[r];
      pval[off + base1 + r] = bv[4 + r]; pidx[off + base1 + r] = bi[4 + r];
    }
  }
}

// ---------------------------------------------------------------------------
// K4 v6: fused merge + gather + loss + out-GEMM. 512 blocks x 4 waves
// (R2-proven structure); loss finale folded in via one atomicAdd per block
// (mechanism verified in R7) — k_loss_final dispatch deleted.
__global__ __launch_bounds__(256) void k_out(
    const float* __restrict__ cn, const float* __restrict__ zn,
    const float* __restrict__ pval, const int* __restrict__ pidx,
    const unsigned short* __restrict__ w_out_sw,
    const float* __restrict__ b_out, float* __restrict__ out,
    float* __restrict__ idx_f, float* __restrict__ loss_f) {
  const int tid = threadIdx.x, w = tid >> 6, l = tid & 63;
  const int lo = l & 15, hi = l >> 4;
  const int r0 = blockIdx.x * 16;
  const int row = r0 + lo;

  // merge 16 code-slice partials (ascending q + strict > => lowest index)
  float v = pval[row];
  int ix = pidx[row];
  #pragma unroll
  for (int q = 1; q < 16; ++q) {
    float vq = pval[q * N_ROWS + row];
    int iq = pidx[q * N_ROWS + row];
    if (vq > v) { v = vq; ix = iq; }
  }
  if (w == 0 && hi == 0) idx_f[row] = (float)ix;

  // gather cn[ix], zn[row] in A-frag order; limb-split; loss partial
  bf16x8 A[2][3];
  float lp = 0.0f;
  #pragma unroll
  for (int c = 0; c < 2; ++c) {
    const float* cp = cn + (size_t)ix * D_DIM + c * 32 + hi * 8;
    const float* zp = zn + (size_t)row * D_DIM + c * 32 + hi * 8;
    float4 c0 = *(const float4*)cp, c1 = *(const float4*)(cp + 4);
    float4 z0 = *(const float4*)zp, z1 = *(const float4*)(zp + 4);
    float xs[8] = {c0.x, c0.y, c0.z, c0.w, c1.x, c1.y, c1.z, c1.w};
    float zs[8] = {z0.x, z0.y, z0.z, z0.w, z1.x, z1.y, z1.z, z1.w};
    limb3(xs, A[c][0], A[c][1], A[c][2]);
    #pragma unroll
    for (int j = 0; j < 8; ++j) { float d = xs[j] - zs[j]; lp += d * d; }
  }
  if (w == 0) {
    #pragma unroll
    for (int m = 1; m < 64; m <<= 1) lp += __shfl_xor(lp, m);
    if (l == 0) atomicAdd(loss_f, lp * (1.25f / (float)(N_ROWS * D_DIM)));
  }

  const bf16x8* Bptr = (const bf16x8*)w_out_sw;
  const int cgb = w * 8;                  // this wave's 8 column-groups
  bf16x8 Bu[6], Bv[6];
  #pragma unroll
  for (int i = 0; i < 6; ++i) Bu[i] = Bptr[((size_t)cgb * 6 + i) * 64 + l];

  #define OSTEP(BCUR, BNXT, CG)                                               \
    {                                                                         \
      _Pragma("unroll")                                                       \
      for (int i = 0; i < 6; ++i)                                             \
        BNXT[i] = Bptr[((size_t)((CG) + 1) * 6 + i) * 64 + l];                \
      f32x4 a0 = {0.f,0.f,0.f,0.f}, a1 = {0.f,0.f,0.f,0.f};                   \
      a0 = __builtin_amdgcn_mfma_f32_16x16x32_bf16(A[0][0], BCUR[0], a0, 0,0,0); \
      a1 = __builtin_amdgcn_mfma_f32_16x16x32_bf16(A[1][0], BCUR[3], a1, 0,0,0); \
      a0 = __builtin_amdgcn_mfma_f32_16x16x32_bf16(A[0][0], BCUR[1], a0, 0,0,0); \
      a1 = __builtin_amdgcn_mfma_f32_16x16x32_bf16(A[1][0], BCUR[4], a1, 0,0,0); \
      a0 = __builtin_amdgcn_mfma_f32_16x16x32_bf16(A[0][1], BCUR[0], a0, 0,0,0); \
      a1 = __builtin_amdgcn_mfma_f32_16x16x32_bf16(A[1][1], BCUR[3], a1, 0,0,0); \
      a0 = __builtin_amdgcn_mfma_f32_16x16x32_bf16(A[0][0], BCUR[2], a0, 0,0,0); \
      a1 = __builtin_amdgcn_mfma_f32_16x16x32_bf16(A[1][0], BCUR[5], a1, 0,0,0); \
      a0 = __builtin_amdgcn_mfma_f32_16x16x32_bf16(A[0][2], BCUR[0], a0, 0,0,0); \
      a1 = __builtin_amdgcn_mfma_f32_16x16x32_bf16(A[1][2], BCUR[3], a1, 0,0,0); \
      a0 = __builtin_amdgcn_mfma_f32_16x16x32_bf16(A[0][1], BCUR[1], a0, 0,0,0); \
      a1 = __builtin_amdgcn_mfma_f32_16x16x32_bf16(A[1][1], BCUR[4], a1, 0,0,0); \
      float bb = b_out[(CG) * 16 + lo];                                       \
      _Pragma("unroll")                                                       \
      for (int r = 0; r < 4; ++r)                                             \
        out[(size_t)(r0 + hi * 4 + r) * F_DIM + (CG) * 16 + lo] =             \
            a0[r] + a1[r] + bb;                                               \
    }

  for (int cg = cgb; cg < cgb + 8; cg += 2) {
    OSTEP(Bu, Bv, cg)          // w=3, cg=31's prefetch over-reads 6KB past
    OSTEP(Bv, Bu, cg + 1)      // wout_sw (lands in pval scratch - harmless)
  }
  #undef OSTEP
}

// ---------------------------------------------------------------------------
extern "C" void kernel_launch(void* const* d_in, const int* in_sizes, int n_in,
                              void* d_out, int out_size, void* d_ws, size_t ws_size,
                              hipStream_t stream) {
  const float* z        = (const float*)d_in[0];
  const float* W_in     = (const float*)d_in[1];
  const float* b_in     = (const float*)d_in[2];
  const float* codebook = (const float*)d_in[3];
  const float* W_out    = (const float*)d_in[4];
  const float* b_out    = (const float*)d_in[5];

  float* outp   = (float*)d_out;                      // Output 0: [8192 x 512]
  float* loss_f = outp + (size_t)N_ROWS * F_DIM;      // Output 1
  float* idx_f  = loss_f + 1;                         // Output 2

  // workspace layout (float units)
  float* wsf = (float*)d_ws;
  float* zn_ws = wsf;                                         // [0, 524288)
  float* cn_ws = wsf + 524288;                                // [524288, 1048576)
  unsigned short* zn_sw = (unsigned short*)(wsf + 1048576);   // 786432 f
  unsigned short* cn_sw = (unsigned short*)(wsf + 1835008);   // 786432 f, ends 2621440
  // 16 KB pad @ [2621440, 2625536) (legacy over-read pad, kept)
  unsigned short* win_sw  = (unsigned short*)(wsf + 2625536); // 49152 f
  unsigned short* wout_sw = (unsigned short*)(wsf + 2674688); // 49152 f, ends 2723840
  float* pval_ws = wsf + 2723840;                             // 131072 f (16 x 8192)
  int*   pidx_ws = (int*)(wsf + 2854912);                     // 131072 ints
  // total 2985984 floats ~ 11.9 MB

  hipLaunchKernelGGL(k_prep, dim3(160), dim3(256), 0, stream,
                     W_in, W_out, codebook, win_sw, wout_sw, cn_ws, cn_sw,
                     loss_f);
  hipLaunchKernelGGL(k_zn, dim3(512), dim3(256), 0, stream,
                     z, win_sw, b_in, zn_ws, zn_sw);
  hipLaunchKernelGGL(k_argmax, dim3(64, 16), dim3(256), 0, stream,
                     zn_sw, cn_sw, pval_ws, pidx_ws);
  hipLaunchKernelGGL(k_out, dim3(512), dim3(256), 0, stream,
                     cn_ws, zn_ws, pval_ws, pidx_ws, wout_sw, b_out,
                     outp, idx_f, loss_f);
}

// Round 10
// 141.257 us; speedup vs baseline: 1.0363x; 1.0363x over previous
//
#include <hip/hip_runtime.h>
#include <hip/hip_bf16.h>

// Problem constants
#define N_ROWS 8192
#define F_DIM  512
#define D_DIM  64
#define C_CODES 8192

typedef __attribute__((ext_vector_type(8))) short bf16x8;   // 8 bf16 = 4 VGPRs
typedef __attribute__((ext_vector_type(4))) float f32x4;

__device__ __forceinline__ unsigned short rne_bf16(float x) {
  unsigned u = __float_as_uint(x);
  return (unsigned short)((u + 0x7FFFu + ((u >> 16) & 1u)) >> 16);
}
__device__ __forceinline__ float bf16_to_f(unsigned short u) {
  return __uint_as_float(((unsigned)u) << 16);
}
// split 8 floats into 3 bf16 limbs (h+m+l reproduces x to ~2^-24 rel)
__device__ __forceinline__ void limb3(const float* xs, bf16x8& H, bf16x8& M, bf16x8& L) {
  #pragma unroll
  for (int j = 0; j < 8; ++j) {
    float x = xs[j];
    unsigned short h = rne_bf16(x);
    float r1 = x - bf16_to_f(h);
    unsigned short m = rne_bf16(r1);
    float r2 = r1 - bf16_to_f(m);
    unsigned short lo = rne_bf16(r2);
    H[j] = (short)h; M[j] = (short)m; L[j] = (short)lo;
  }
}

// async global->LDS, 16B per lane; LDS dest is wave-uniform base + lane*16
typedef __attribute__((address_space(1))) const unsigned char gas_uchar;
typedef __attribute__((address_space(3))) unsigned char las_uchar;
__device__ __forceinline__ void gld_lds16(const void* g, void* l) {
  __builtin_amdgcn_global_load_lds((gas_uchar*)g, (las_uchar*)l, 16, 0, 0);
}

// ---------------------------------------------------------------------------
// K0: fused prep — W_in swizzle (blocks 0..15), W_out swizzle (16..31),
// codebook normalize + frag emit (32..159). Also zero-inits the loss output
// (k_out atomically accumulates into it; stream order guarantees init-first).
__global__ __launch_bounds__(256) void k_prep(
    const float* __restrict__ W_in, const float* __restrict__ W_out,
    const float* __restrict__ cb,
    unsigned short* __restrict__ win_sw, unsigned short* __restrict__ wout_sw,
    float* __restrict__ cn, unsigned short* __restrict__ cn_sw,
    float* __restrict__ loss_f) {
  const int tid = threadIdx.x, w = tid >> 6, l = tid & 63;
  const int lo = l & 15, hi = l >> 4;
  const int bid = blockIdx.x;
  if (bid == 0 && tid == 0) loss_f[0] = 0.0f;

  if (bid < 16) {
    // W_in [512][64] -> frags ((kc*4+cg)*3+m)*512 + l*8 + j
    const int task = bid * 4 + w;           // 0..63
    const int kc = task >> 2, cg = task & 3;
    float xs[8];
    #pragma unroll
    for (int j = 0; j < 8; ++j)
      xs[j] = W_in[(size_t)(kc * 32 + hi * 8 + j) * D_DIM + cg * 16 + lo];
    bf16x8 H, M, L;
    limb3(xs, H, M, L);
    const int fb = (kc * 4 + cg) * 3;
    unsigned short* d0 = win_sw + (size_t)(fb + 0) * 512 + l * 8;
    *(bf16x8*)d0 = H;
    *(bf16x8*)(d0 + 512) = M;
    *(bf16x8*)(d0 + 1024) = L;
  } else if (bid < 32) {
    // W_out [64][512] -> frags ((cg*2+c)*3+m)*512 + l*8 + j
    const int task = (bid - 16) * 4 + w;    // 0..63
    const int cg = task >> 1, c = task & 1;
    float xs[8];
    #pragma unroll
    for (int j = 0; j < 8; ++j)
      xs[j] = W_out[(size_t)(c * 32 + hi * 8 + j) * F_DIM + cg * 16 + lo];
    bf16x8 H, M, L;
    limb3(xs, H, M, L);
    const int fb = (cg * 2 + c) * 3;
    unsigned short* d0 = wout_sw + (size_t)(fb + 0) * 512 + l * 8;
    *(bf16x8*)d0 = H;
    *(bf16x8*)(d0 + 512) = M;
    *(bf16x8*)(d0 + 1024) = L;
  } else {
    // cn = normalise(codebook): fp32 rows + 3-limb frags
    const int g = (bid - 32) * 4 + w;       // 0..511
    const int code = g * 16 + lo;
    float xs[2][8];
    float s = 0.0f;
    #pragma unroll
    for (int c = 0; c < 2; ++c) {
      const float* sp = cb + (size_t)code * D_DIM + c * 32 + hi * 8;
      float4 a = *(const float4*)sp, b = *(const float4*)(sp + 4);
      xs[c][0]=a.x; xs[c][1]=a.y; xs[c][2]=a.z; xs[c][3]=a.w;
      xs[c][4]=b.x; xs[c][5]=b.y; xs[c][6]=b.z; xs[c][7]=b.w;
      #pragma unroll
      for (int j = 0; j < 8; ++j) s += xs[c][j] * xs[c][j];
    }
    s += __shfl_xor(s, 16);
    s += __shfl_xor(s, 32);
    float inv = rsqrtf(s * (1.0f / 64.0f) + 1e-12f);
    #pragma unroll
    for (int c = 0; c < 2; ++c) {
      #pragma unroll
      for (int j = 0; j < 8; ++j) xs[c][j] *= inv;
      float* dp = cn + (size_t)code * D_DIM + c * 32 + hi * 8;
      *(float4*)dp = make_float4(xs[c][0], xs[c][1], xs[c][2], xs[c][3]);
      *(float4*)(dp + 4) = make_float4(xs[c][4], xs[c][5], xs[c][6], xs[c][7]);
      bf16x8 H, M, L;
      limb3(xs[c], H, M, L);
      const int fb = (g * 2 + c) * 3;
      unsigned short* d0 = cn_sw + (size_t)(fb + 0) * 512 + l * 8;
      *(bf16x8*)d0 = H;
      *(bf16x8*)(d0 + 512) = M;
      *(bf16x8*)(d0 + 1024) = L;
    }
  }
}

// ---------------------------------------------------------------------------
// K1 v4 (R2-proven): zn = normalise(z @ W_in + b_in). 512 blocks x 4 waves:
// K=512 split as 128 per wave (4 kc-chunks), LDS cross-wave reduce,
// per-wave normalize. Direct global z loads + register B ping-pong.
__global__ __launch_bounds__(256) void k_zn(
    const float* __restrict__ z, const unsigned short* __restrict__ w_in_sw,
    const float* __restrict__ b_in, float* __restrict__ zn,
    unsigned short* __restrict__ zn_sw) {
  __shared__ float red[4096];        // [w][cg][r][lane] scalar layout
  __shared__ float t_lds[16 * 65];
  const int tid = threadIdx.x, w = tid >> 6, l = tid & 63;
  const int lo = l & 15, hi = l >> 4;
  const int g = blockIdx.x;          // 16-row group
  const int r0 = g * 16;
  const int kcb = w * 4;             // this wave's K-quarter (4 kc-chunks)
  const bf16x8* Bptr = (const bf16x8*)w_in_sw;
  const float* zbase = z + (size_t)(r0 + lo) * F_DIM + hi * 8;

  f32x4 acc[4];
  #pragma unroll
  for (int cg = 0; cg < 4; ++cg) acc[cg] = (f32x4){0.f, 0.f, 0.f, 0.f};

  bf16x8 Bu[12], Bv[12];
  #pragma unroll
  for (int i = 0; i < 12; ++i) Bu[i] = Bptr[((size_t)kcb * 12 + i) * 64 + l];
  float4 za = *(const float4*)(zbase + kcb * 32);
  float4 zb = *(const float4*)(zbase + kcb * 32 + 4);

  #define ZMFMA(BCUR)                                                         \
    {                                                                         \
      float xs[8] = {za.x, za.y, za.z, za.w, zb.x, zb.y, zb.z, zb.w};         \
      bf16x8 Ah, Am, Al;                                                      \
      limb3(xs, Ah, Am, Al);                                                  \
      _Pragma("unroll")                                                       \
      for (int cg = 0; cg < 4; ++cg) {                                        \
        f32x4 t = acc[cg];                                                    \
        t = __builtin_amdgcn_mfma_f32_16x16x32_bf16(Ah, BCUR[cg*3+0], t, 0,0,0); \
        t = __builtin_amdgcn_mfma_f32_16x16x32_bf16(Ah, BCUR[cg*3+1], t, 0,0,0); \
        t = __builtin_amdgcn_mfma_f32_16x16x32_bf16(Am, BCUR[cg*3+0], t, 0,0,0); \
        t = __builtin_amdgcn_mfma_f32_16x16x32_bf16(Ah, BCUR[cg*3+2], t, 0,0,0); \
        t = __builtin_amdgcn_mfma_f32_16x16x32_bf16(Al, BCUR[cg*3+0], t, 0,0,0); \
        t = __builtin_amdgcn_mfma_f32_16x16x32_bf16(Am, BCUR[cg*3+1], t, 0,0,0); \
        acc[cg] = t;                                                          \
      }                                                                       \
    }

  {  // step 0: compute kcb, prefetch kcb+1 into Bv
    float4 na = *(const float4*)(zbase + (kcb + 1) * 32);
    float4 nb = *(const float4*)(zbase + (kcb + 1) * 32 + 4);
    #pragma unroll
    for (int i = 0; i < 12; ++i) Bv[i] = Bptr[((size_t)(kcb + 1) * 12 + i) * 64 + l];
    ZMFMA(Bu)
    za = na; zb = nb;
  }
  {  // step 1
    float4 na = *(const float4*)(zbase + (kcb + 2) * 32);
    float4 nb = *(const float4*)(zbase + (kcb + 2) * 32 + 4);
    #pragma unroll
    for (int i = 0; i < 12; ++i) Bu[i] = Bptr[((size_t)(kcb + 2) * 12 + i) * 64 + l];
    ZMFMA(Bv)
    za = na; zb = nb;
  }
  {  // step 2
    float4 na = *(const float4*)(zbase + (kcb + 3) * 32);
    float4 nb = *(const float4*)(zbase + (kcb + 3) * 32 + 4);
    #pragma unroll
    for (int i = 0; i < 12; ++i) Bv[i] = Bptr[((size_t)(kcb + 3) * 12 + i) * 64 + l];
    ZMFMA(Bu)
    za = na; zb = nb;
  }
  ZMFMA(Bv)   // step 3: no prefetch
  #undef ZMFMA

  // cross-wave K reduction (conflict-free scalar layout, stride-1 lanes)
  #pragma unroll
  for (int cg = 0; cg < 4; ++cg)
    #pragma unroll
    for (int r = 0; r < 4; ++r)
      red[((w * 4 + cg) * 4 + r) * 64 + l] = acc[cg][r];
  __syncthreads();

  // wave w normalizes output rows hi*4 + w
  {
    float v[4], s = 0.0f;
    #pragma unroll
    for (int cg = 0; cg < 4; ++cg) {
      float t = b_in[cg * 16 + lo];
      #pragma unroll
      for (int w2 = 0; w2 < 4; ++w2) t += red[((w2 * 4 + cg) * 4 + w) * 64 + l];
      v[cg] = t; s += t * t;
    }
    s += __shfl_xor(s, 1);
    s += __shfl_xor(s, 2);
    s += __shfl_xor(s, 4);
    s += __shfl_xor(s, 8);
    float inv = rsqrtf(s * (1.0f / 64.0f) + 1e-12f);
    #pragma unroll
    for (int cg = 0; cg < 4; ++cg)
      t_lds[(hi * 4 + w) * 65 + cg * 16 + lo] = v[cg] * inv;
  }
  __syncthreads();

  // waves 0,1 emit fp32 + frags (A-frag order: row = lo, ks = c*32+hi*8+j)
  if (w < 2) {
    const int c = w;
    float xs[8];
    #pragma unroll
    for (int j = 0; j < 8; ++j) xs[j] = t_lds[lo * 65 + c * 32 + hi * 8 + j];
    float* dp = zn + (size_t)(r0 + lo) * D_DIM + c * 32 + hi * 8;
    *(float4*)dp = make_float4(xs[0], xs[1], xs[2], xs[3]);
    *(float4*)(dp + 4) = make_float4(xs[4], xs[5], xs[6], xs[7]);
    bf16x8 H, M, L;
    limb3(xs, H, M, L);
    const int fb = (g * 2 + c) * 3;
    unsigned short* d0 = zn_sw + (size_t)(fb + 0) * 512 + l * 8;
    *(bf16x8*)d0 = H;
    *(bf16x8*)(d0 + 512) = M;
    *(bf16x8*)(d0 + 1024) = L;
  }
}

// ---------------------------------------------------------------------------
// K3 v9: 16x16x32 MFMA argmax, R2-proven schedule idiom, but 8 waves/block
// and 4 B-groups per step: barrier count 16 -> 8 (the per-step vmcnt(0)
// drain is the measured ~20% stall; R6 showed hand-rolled vmcnt regresses
// because sched_barrier kills compiler interleave — so halve the drain
// COUNT instead, keeping __syncthreads). Grid (32,16) x 512 thr = same
// 4 waves/SIMD; LDS 2 x 24KB = 48KB, 2 blocks/CU. Candidate order and
// per-candidate math bit-identical to R2.
__global__ __launch_bounds__(512) void k_argmax(
    const unsigned short* __restrict__ zn_sw,
    const unsigned short* __restrict__ cn_sw,
    float* __restrict__ pval, int* __restrict__ pidx) {
  __shared__ short smem[2 * 24 * 512];        // 2 bufs x 24 frags x 1KB
  const int tid = threadIdx.x;
  const int w = tid >> 6, l = tid & 63;       // w in 0..7
  const int lo = l & 15, hi = l >> 4;
  const int gA0 = (blockIdx.x * 8 + w) * 2;   // 0..510 (16-row groups)
  const int gB0 = blockIdx.y * 32;            // B group base (32 groups/slice)
  const bf16x8* Ab = (const bf16x8*)zn_sw;
  const char* Bbytes = (const char*)cn_sw;

  bf16x8 A0[2][3], A1[2][3];
  #pragma unroll
  for (int c = 0; c < 2; ++c)
    #pragma unroll
    for (int m = 0; m < 3; ++m) {
      A0[c][m] = Ab[(size_t)((gA0 * 2 + c) * 3 + m) * 64 + l];
      A1[c][m] = Ab[(size_t)(((gA0 + 1) * 2 + c) * 3 + m) * 64 + l];
    }

  float bv[8];
  int bi[8];
  #pragma unroll
  for (int i = 0; i < 8; ++i) { bv[i] = -1e30f; bi[i] = 0; }
  int cand = blockIdx.y * 512 + lo;

  // stage step s (4 groups = 24 contiguous 1KB frags) into buffer b;
  // wave w copies frags w*3 .. w*3+2 (8 waves x 3 = 24). Dest wave-uniform.
  #define STAGE(b, s)                                                         \
    {                                                                         \
      const int fb = (gB0 + (s) * 4) * 6 + w * 3;                             \
      _Pragma("unroll")                                                       \
      for (int i = 0; i < 3; ++i)                                             \
        gld_lds16(Bbytes + ((size_t)(fb + i) << 10) + (size_t)l * 16,         \
                  &smem[((b) * 24 + w * 3 + i) * 512]);                       \
    }

  #define MF(A_, B_, C_) __builtin_amdgcn_mfma_f32_16x16x32_bf16(A_, B_, C_, 0, 0, 0)

  // one 16-code group: B frags at local frag base LF (c*3+m layout)
  #define COMPUTE(LF)                                                         \
    {                                                                         \
      bf16x8 Bf[6];                                                           \
      _Pragma("unroll")                                                       \
      for (int i = 0; i < 6; ++i)                                             \
        Bf[i] = *(const bf16x8*)&smem[((LF) + i) * 512 + l * 8];              \
      f32x4 a0 = {0.f,0.f,0.f,0.f}, a1 = {0.f,0.f,0.f,0.f};                   \
      f32x4 a2 = {0.f,0.f,0.f,0.f}, a3 = {0.f,0.f,0.f,0.f};                   \
      a0 = MF(A0[0][0], Bf[0], a0); a1 = MF(A0[1][0], Bf[3], a1);             \
      a2 = MF(A1[0][0], Bf[0], a2); a3 = MF(A1[1][0], Bf[3], a3);             \
      a0 = MF(A0[0][0], Bf[1], a0); a1 = MF(A0[1][0], Bf[4], a1);             \
      a2 = MF(A1[0][0], Bf[1], a2); a3 = MF(A1[1][0], Bf[4], a3);             \
      a0 = MF(A0[0][1], Bf[0], a0); a1 = MF(A0[1][1], Bf[3], a1);             \
      a2 = MF(A1[0][1], Bf[0], a2); a3 = MF(A1[1][1], Bf[3], a3);             \
      a0 = MF(A0[0][0], Bf[2], a0); a1 = MF(A0[1][0], Bf[5], a1);             \
      a2 = MF(A1[0][0], Bf[2], a2); a3 = MF(A1[1][0], Bf[5], a3);             \
      a0 = MF(A0[0][2], Bf[0], a0); a1 = MF(A0[1][2], Bf[3], a1);             \
      a2 = MF(A1[0][2], Bf[0], a2); a3 = MF(A1[1][2], Bf[3], a3);             \
      a0 = MF(A0[0][1], Bf[1], a0); a1 = MF(A0[1][1], Bf[4], a1);             \
      a2 = MF(A1[0][1], Bf[1], a2); a3 = MF(A1[1][1], Bf[4], a3);             \
      _Pragma("unroll")                                                       \
      for (int r = 0; r < 4; ++r) {                                           \
        float d0 = a0[r] + a1[r];                                             \
        if (d0 > bv[r]) { bv[r] = d0; bi[r] = cand; }                         \
        float d1 = a2[r] + a3[r];                                             \
        if (d1 > bv[4 + r]) { bv[4 + r] = d1; bi[4 + r] = cand; }             \
      }                                                                       \
      cand += 16;                                                             \
    }

  STAGE(0, 0)
  __syncthreads();
  int cur = 0;
  for (int s = 0; s < 8; ++s) {
    if (s < 7) STAGE(cur ^ 1, s + 1)
    COMPUTE(cur * 24 + 0)
    COMPUTE(cur * 24 + 6)
    COMPUTE(cur * 24 + 12)
    COMPUTE(cur * 24 + 18)
    __syncthreads();      // drains stage loads; protects buffer reuse
    cur ^= 1;
  }
  #undef STAGE
  #undef COMPUTE
  #undef MF

  #pragma unroll
  for (int i = 0; i < 8; ++i) {
    float v = bv[i]; int ix = bi[i];
    #pragma unroll
    for (int m = 1; m < 16; m <<= 1) {
      float ov = __shfl_xor(v, m);
      int oi = __shfl_xor(ix, m);
      if (ov > v || (ov == v && oi < ix)) { v = ov; ix = oi; }
    }
    bv[i] = v; bi[i] = ix;
  }
  if (lo == 0) {
    int off = blockIdx.y * N_ROWS;
    int base0 = gA0 * 16 + hi * 4;
    int base1 = (gA0 + 1) * 16 + hi * 4;
    #pragma unroll
    for (int r = 0; r < 4; ++r) {
      pval[off + base0 + r] = bv[r];     pidx[off + base0 + r] = bi[r];
      pval[off + base1 + r] = bv[4 + r]; pidx[off + base1 + r] = bi[4 + r];
    }
  }
}

// ---------------------------------------------------------------------------
// K4 v6: fused merge + gather + loss + out-GEMM. 512 blocks x 4 waves
// (R2-proven structure); loss finale folded in via one atomicAdd per block
// (mechanism verified in R7/R9) — k_loss_final dispatch deleted.
__global__ __launch_bounds__(256) void k_out(
    const float* __restrict__ cn, const float* __restrict__ zn,
    const float* __restrict__ pval, const int* __restrict__ pidx,
    const unsigned short* __restrict__ w_out_sw,
    const float* __restrict__ b_out, float* __restrict__ out,
    float* __restrict__ idx_f, float* __restrict__ loss_f) {
  const int tid = threadIdx.x, w = tid >> 6, l = tid & 63;
  const int lo = l & 15, hi = l >> 4;
  const int r0 = blockIdx.x * 16;
  const int row = r0 + lo;

  // merge 16 code-slice partials (ascending q + strict > => lowest index)
  float v = pval[row];
  int ix = pidx[row];
  #pragma unroll
  for (int q = 1; q < 16; ++q) {
    float vq = pval[q * N_ROWS + row];
    int iq = pidx[q * N_ROWS + row];
    if (vq > v) { v = vq; ix = iq; }
  }
  if (w == 0 && hi == 0) idx_f[row] = (float)ix;

  // gather cn[ix], zn[row] in A-frag order; limb-split; loss partial
  bf16x8 A[2][3];
  float lp = 0.0f;
  #pragma unroll
  for (int c = 0; c < 2; ++c) {
    const float* cp = cn + (size_t)ix * D_DIM + c * 32 + hi * 8;
    const float* zp = zn + (size_t)row * D_DIM + c * 32 + hi * 8;
    float4 c0 = *(const float4*)cp, c1 = *(const float4*)(cp + 4);
    float4 z0 = *(const float4*)zp, z1 = *(const float4*)(zp + 4);
    float xs[8] = {c0.x, c0.y, c0.z, c0.w, c1.x, c1.y, c1.z, c1.w};
    float zs[8] = {z0.x, z0.y, z0.z, z0.w, z1.x, z1.y, z1.z, z1.w};
    limb3(xs, A[c][0], A[c][1], A[c][2]);
    #pragma unroll
    for (int j = 0; j < 8; ++j) { float d = xs[j] - zs[j]; lp += d * d; }
  }
  if (w == 0) {
    #pragma unroll
    for (int m = 1; m < 64; m <<= 1) lp += __shfl_xor(lp, m);
    if (l == 0) atomicAdd(loss_f, lp * (1.25f / (float)(N_ROWS * D_DIM)));
  }

  const bf16x8* Bptr = (const bf16x8*)w_out_sw;
  const int cgb = w * 8;                  // this wave's 8 column-groups
  bf16x8 Bu[6], Bv[6];
  #pragma unroll
  for (int i = 0; i < 6; ++i) Bu[i] = Bptr[((size_t)cgb * 6 + i) * 64 + l];

  #define OSTEP(BCUR, BNXT, CG)                                               \
    {                                                                         \
      _Pragma("unroll")                                                       \
      for (int i = 0; i < 6; ++i)                                             \
        BNXT[i] = Bptr[((size_t)((CG) + 1) * 6 + i) * 64 + l];                \
      f32x4 a0 = {0.f,0.f,0.f,0.f}, a1 = {0.f,0.f,0.f,0.f};                   \
      a0 = __builtin_amdgcn_mfma_f32_16x16x32_bf16(A[0][0], BCUR[0], a0, 0,0,0); \
      a1 = __builtin_amdgcn_mfma_f32_16x16x32_bf16(A[1][0], BCUR[3], a1, 0,0,0); \
      a0 = __builtin_amdgcn_mfma_f32_16x16x32_bf16(A[0][0], BCUR[1], a0, 0,0,0); \
      a1 = __builtin_amdgcn_mfma_f32_16x16x32_bf16(A[1][0], BCUR[4], a1, 0,0,0); \
      a0 = __builtin_amdgcn_mfma_f32_16x16x32_bf16(A[0][1], BCUR[0], a0, 0,0,0); \
      a1 = __builtin_amdgcn_mfma_f32_16x16x32_bf16(A[1][1], BCUR[3], a1, 0,0,0); \
      a0 = __builtin_amdgcn_mfma_f32_16x16x32_bf16(A[0][0], BCUR[2], a0, 0,0,0); \
      a1 = __builtin_amdgcn_mfma_f32_16x16x32_bf16(A[1][0], BCUR[5], a1, 0,0,0); \
      a0 = __builtin_amdgcn_mfma_f32_16x16x32_bf16(A[0][2], BCUR[0], a0, 0,0,0); \
      a1 = __builtin_amdgcn_mfma_f32_16x16x32_bf16(A[1][2], BCUR[3], a1, 0,0,0); \
      a0 = __builtin_amdgcn_mfma_f32_16x16x32_bf16(A[0][1], BCUR[1], a0, 0,0,0); \
      a1 = __builtin_amdgcn_mfma_f32_16x16x32_bf16(A[1][1], BCUR[4], a1, 0,0,0); \
      float bb = b_out[(CG) * 16 + lo];                                       \
      _Pragma("unroll")                                                       \
      for (int r = 0; r < 4; ++r)                                             \
        out[(size_t)(r0 + hi * 4 + r) * F_DIM + (CG) * 16 + lo] =             \
            a0[r] + a1[r] + bb;                                               \
    }

  for (int cg = cgb; cg < cgb + 8; cg += 2) {
    OSTEP(Bu, Bv, cg)          // w=3, cg=31's prefetch over-reads 6KB past
    OSTEP(Bv, Bu, cg + 1)      // wout_sw (lands in pval scratch - harmless)
  }
  #undef OSTEP
}

// ---------------------------------------------------------------------------
extern "C" void kernel_launch(void* const* d_in, const int* in_sizes, int n_in,
                              void* d_out, int out_size, void* d_ws, size_t ws_size,
                              hipStream_t stream) {
  const float* z        = (const float*)d_in[0];
  const float* W_in     = (const float*)d_in[1];
  const float* b_in     = (const float*)d_in[2];
  const float* codebook = (const float*)d_in[3];
  const float* W_out    = (const float*)d_in[4];
  const float* b_out    = (const float*)d_in[5];

  float* outp   = (float*)d_out;                      // Output 0: [8192 x 512]
  float* loss_f = outp + (size_t)N_ROWS * F_DIM;      // Output 1
  float* idx_f  = loss_f + 1;                         // Output 2

  // workspace layout (float units)
  float* wsf = (float*)d_ws;
  float* zn_ws = wsf;                                         // [0, 524288)
  float* cn_ws = wsf + 524288;                                // [524288, 1048576)
  unsigned short* zn_sw = (unsigned short*)(wsf + 1048576);   // 786432 f
  unsigned short* cn_sw = (unsigned short*)(wsf + 1835008);   // 786432 f, ends 2621440
  // 16 KB pad @ [2621440, 2625536) (legacy over-read pad, kept)
  unsigned short* win_sw  = (unsigned short*)(wsf + 2625536); // 49152 f
  unsigned short* wout_sw = (unsigned short*)(wsf + 2674688); // 49152 f, ends 2723840
  float* pval_ws = wsf + 2723840;                             // 131072 f (16 x 8192)
  int*   pidx_ws = (int*)(wsf + 2854912);                     // 131072 ints
  // total 2985984 floats ~ 11.9 MB

  hipLaunchKernelGGL(k_prep, dim3(160), dim3(256), 0, stream,
                     W_in, W_out, codebook, win_sw, wout_sw, cn_ws, cn_sw,
                     loss_f);
  hipLaunchKernelGGL(k_zn, dim3(512), dim3(256), 0, stream,
                     z, win_sw, b_in, zn_ws, zn_sw);
  hipLaunchKernelGGL(k_argmax, dim3(32, 16), dim3(512), 0, stream,
                     zn_sw, cn_sw, pval_ws, pidx_ws);
  hipLaunchKernelGGL(k_out, dim3(512), dim3(256), 0, stream,
                     cn_ws, zn_ws, pval_ws, pidx_ws, wout_sw, b_out,
                     outp, idx_f, loss_f);
}

// Round 11
// 139.879 us; speedup vs baseline: 1.0465x; 1.0099x over previous
//
#include <hip/hip_runtime.h>
#include <hip/hip_bf16.h>

// Problem constants
#define N_ROWS 8192
#define F_DIM  512
#define D_DIM  64
#define C_CODES 8192

typedef __attribute__((ext_vector_type(8))) short bf16x8;   // 8 bf16 = 4 VGPRs
typedef __attribute__((ext_vector_type(4))) float f32x4;

__device__ __forceinline__ unsigned short rne_bf16(float x) {
  unsigned u = __float_as_uint(x);
  return (unsigned short)((u + 0x7FFFu + ((u >> 16) & 1u)) >> 16);
}
__device__ __forceinline__ float bf16_to_f(unsigned short u) {
  return __uint_as_float(((unsigned)u) << 16);
}
// split 8 floats into 3 bf16 limbs (h+m+l reproduces x to ~2^-24 rel)
__device__ __forceinline__ void limb3(const float* xs, bf16x8& H, bf16x8& M, bf16x8& L) {
  #pragma unroll
  for (int j = 0; j < 8; ++j) {
    float x = xs[j];
    unsigned short h = rne_bf16(x);
    float r1 = x - bf16_to_f(h);
    unsigned short m = rne_bf16(r1);
    float r2 = r1 - bf16_to_f(m);
    unsigned short lo = rne_bf16(r2);
    H[j] = (short)h; M[j] = (short)m; L[j] = (short)lo;
  }
}

// async global->LDS, 16B per lane; LDS dest is wave-uniform base + lane*16
typedef __attribute__((address_space(1))) const unsigned char gas_uchar;
typedef __attribute__((address_space(3))) unsigned char las_uchar;
__device__ __forceinline__ void gld_lds16(const void* g, void* l) {
  __builtin_amdgcn_global_load_lds((gas_uchar*)g, (las_uchar*)l, 16, 0, 0);
}

// ---------------------------------------------------------------------------
// K0: fused prep — W_in swizzle (blocks 0..15), W_out swizzle (16..31),
// codebook normalize + frag emit (32..159). Block 0 additionally zero-inits
// the loss output and the packed argmax best[] array (key 0 < any real key;
// stream order guarantees init completes before k_argmax).
__global__ __launch_bounds__(256) void k_prep(
    const float* __restrict__ W_in, const float* __restrict__ W_out,
    const float* __restrict__ cb,
    unsigned short* __restrict__ win_sw, unsigned short* __restrict__ wout_sw,
    float* __restrict__ cn, unsigned short* __restrict__ cn_sw,
    float* __restrict__ loss_f, unsigned long long* __restrict__ best) {
  const int tid = threadIdx.x, w = tid >> 6, l = tid & 63;
  const int lo = l & 15, hi = l >> 4;
  const int bid = blockIdx.x;
  if (bid == 0) {
    if (tid == 0) loss_f[0] = 0.0f;
    for (int i = tid; i < N_ROWS; i += 256) best[i] = 0ull;
  }

  if (bid < 16) {
    // W_in [512][64] -> frags ((kc*4+cg)*3+m)*512 + l*8 + j
    const int task = bid * 4 + w;           // 0..63
    const int kc = task >> 2, cg = task & 3;
    float xs[8];
    #pragma unroll
    for (int j = 0; j < 8; ++j)
      xs[j] = W_in[(size_t)(kc * 32 + hi * 8 + j) * D_DIM + cg * 16 + lo];
    bf16x8 H, M, L;
    limb3(xs, H, M, L);
    const int fb = (kc * 4 + cg) * 3;
    unsigned short* d0 = win_sw + (size_t)(fb + 0) * 512 + l * 8;
    *(bf16x8*)d0 = H;
    *(bf16x8*)(d0 + 512) = M;
    *(bf16x8*)(d0 + 1024) = L;
  } else if (bid < 32) {
    // W_out [64][512] -> frags ((cg*2+c)*3+m)*512 + l*8 + j
    const int task = (bid - 16) * 4 + w;    // 0..63
    const int cg = task >> 1, c = task & 1;
    float xs[8];
    #pragma unroll
    for (int j = 0; j < 8; ++j)
      xs[j] = W_out[(size_t)(c * 32 + hi * 8 + j) * F_DIM + cg * 16 + lo];
    bf16x8 H, M, L;
    limb3(xs, H, M, L);
    const int fb = (cg * 2 + c) * 3;
    unsigned short* d0 = wout_sw + (size_t)(fb + 0) * 512 + l * 8;
    *(bf16x8*)d0 = H;
    *(bf16x8*)(d0 + 512) = M;
    *(bf16x8*)(d0 + 1024) = L;
  } else {
    // cn = normalise(codebook): fp32 rows + 3-limb frags
    const int g = (bid - 32) * 4 + w;       // 0..511
    const int code = g * 16 + lo;
    float xs[2][8];
    float s = 0.0f;
    #pragma unroll
    for (int c = 0; c < 2; ++c) {
      const float* sp = cb + (size_t)code * D_DIM + c * 32 + hi * 8;
      float4 a = *(const float4*)sp, b = *(const float4*)(sp + 4);
      xs[c][0]=a.x; xs[c][1]=a.y; xs[c][2]=a.z; xs[c][3]=a.w;
      xs[c][4]=b.x; xs[c][5]=b.y; xs[c][6]=b.z; xs[c][7]=b.w;
      #pragma unroll
      for (int j = 0; j < 8; ++j) s += xs[c][j] * xs[c][j];
    }
    s += __shfl_xor(s, 16);
    s += __shfl_xor(s, 32);
    float inv = rsqrtf(s * (1.0f / 64.0f) + 1e-12f);
    #pragma unroll
    for (int c = 0; c < 2; ++c) {
      #pragma unroll
      for (int j = 0; j < 8; ++j) xs[c][j] *= inv;
      float* dp = cn + (size_t)code * D_DIM + c * 32 + hi * 8;
      *(float4*)dp = make_float4(xs[c][0], xs[c][1], xs[c][2], xs[c][3]);
      *(float4*)(dp + 4) = make_float4(xs[c][4], xs[c][5], xs[c][6], xs[c][7]);
      bf16x8 H, M, L;
      limb3(xs[c], H, M, L);
      const int fb = (g * 2 + c) * 3;
      unsigned short* d0 = cn_sw + (size_t)(fb + 0) * 512 + l * 8;
      *(bf16x8*)d0 = H;
      *(bf16x8*)(d0 + 512) = M;
      *(bf16x8*)(d0 + 1024) = L;
    }
  }
}

// ---------------------------------------------------------------------------
// K1 v4 (R2-proven): zn = normalise(z @ W_in + b_in). 512 blocks x 4 waves:
// K=512 split as 128 per wave (4 kc-chunks), LDS cross-wave reduce,
// per-wave normalize. Direct global z loads + register B ping-pong.
__global__ __launch_bounds__(256) void k_zn(
    const float* __restrict__ z, const unsigned short* __restrict__ w_in_sw,
    const float* __restrict__ b_in, float* __restrict__ zn,
    unsigned short* __restrict__ zn_sw) {
  __shared__ float red[4096];        // [w][cg][r][lane] scalar layout
  __shared__ float t_lds[16 * 65];
  const int tid = threadIdx.x, w = tid >> 6, l = tid & 63;
  const int lo = l & 15, hi = l >> 4;
  const int g = blockIdx.x;          // 16-row group
  const int r0 = g * 16;
  const int kcb = w * 4;             // this wave's K-quarter (4 kc-chunks)
  const bf16x8* Bptr = (const bf16x8*)w_in_sw;
  const float* zbase = z + (size_t)(r0 + lo) * F_DIM + hi * 8;

  f32x4 acc[4];
  #pragma unroll
  for (int cg = 0; cg < 4; ++cg) acc[cg] = (f32x4){0.f, 0.f, 0.f, 0.f};

  bf16x8 Bu[12], Bv[12];
  #pragma unroll
  for (int i = 0; i < 12; ++i) Bu[i] = Bptr[((size_t)kcb * 12 + i) * 64 + l];
  float4 za = *(const float4*)(zbase + kcb * 32);
  float4 zb = *(const float4*)(zbase + kcb * 32 + 4);

  #define ZMFMA(BCUR)                                                         \
    {                                                                         \
      float xs[8] = {za.x, za.y, za.z, za.w, zb.x, zb.y, zb.z, zb.w};         \
      bf16x8 Ah, Am, Al;                                                      \
      limb3(xs, Ah, Am, Al);                                                  \
      _Pragma("unroll")                                                       \
      for (int cg = 0; cg < 4; ++cg) {                                        \
        f32x4 t = acc[cg];                                                    \
        t = __builtin_amdgcn_mfma_f32_16x16x32_bf16(Ah, BCUR[cg*3+0], t, 0,0,0); \
        t = __builtin_amdgcn_mfma_f32_16x16x32_bf16(Ah, BCUR[cg*3+1], t, 0,0,0); \
        t = __builtin_amdgcn_mfma_f32_16x16x32_bf16(Am, BCUR[cg*3+0], t, 0,0,0); \
        t = __builtin_amdgcn_mfma_f32_16x16x32_bf16(Ah, BCUR[cg*3+2], t, 0,0,0); \
        t = __builtin_amdgcn_mfma_f32_16x16x32_bf16(Al, BCUR[cg*3+0], t, 0,0,0); \
        t = __builtin_amdgcn_mfma_f32_16x16x32_bf16(Am, BCUR[cg*3+1], t, 0,0,0); \
        acc[cg] = t;                                                          \
      }                                                                       \
    }

  {  // step 0: compute kcb, prefetch kcb+1 into Bv
    float4 na = *(const float4*)(zbase + (kcb + 1) * 32);
    float4 nb = *(const float4*)(zbase + (kcb + 1) * 32 + 4);
    #pragma unroll
    for (int i = 0; i < 12; ++i) Bv[i] = Bptr[((size_t)(kcb + 1) * 12 + i) * 64 + l];
    ZMFMA(Bu)
    za = na; zb = nb;
  }
  {  // step 1
    float4 na = *(const float4*)(zbase + (kcb + 2) * 32);
    float4 nb = *(const float4*)(zbase + (kcb + 2) * 32 + 4);
    #pragma unroll
    for (int i = 0; i < 12; ++i) Bu[i] = Bptr[((size_t)(kcb + 2) * 12 + i) * 64 + l];
    ZMFMA(Bv)
    za = na; zb = nb;
  }
  {  // step 2
    float4 na = *(const float4*)(zbase + (kcb + 3) * 32);
    float4 nb = *(const float4*)(zbase + (kcb + 3) * 32 + 4);
    #pragma unroll
    for (int i = 0; i < 12; ++i) Bv[i] = Bptr[((size_t)(kcb + 3) * 12 + i) * 64 + l];
    ZMFMA(Bu)
    za = na; zb = nb;
  }
  ZMFMA(Bv)   // step 3: no prefetch
  #undef ZMFMA

  // cross-wave K reduction (conflict-free scalar layout, stride-1 lanes)
  #pragma unroll
  for (int cg = 0; cg < 4; ++cg)
    #pragma unroll
    for (int r = 0; r < 4; ++r)
      red[((w * 4 + cg) * 4 + r) * 64 + l] = acc[cg][r];
  __syncthreads();

  // wave w normalizes output rows hi*4 + w
  {
    float v[4], s = 0.0f;
    #pragma unroll
    for (int cg = 0; cg < 4; ++cg) {
      float t = b_in[cg * 16 + lo];
      #pragma unroll
      for (int w2 = 0; w2 < 4; ++w2) t += red[((w2 * 4 + cg) * 4 + w) * 64 + l];
      v[cg] = t; s += t * t;
    }
    s += __shfl_xor(s, 1);
    s += __shfl_xor(s, 2);
    s += __shfl_xor(s, 4);
    s += __shfl_xor(s, 8);
    float inv = rsqrtf(s * (1.0f / 64.0f) + 1e-12f);
    #pragma unroll
    for (int cg = 0; cg < 4; ++cg)
      t_lds[(hi * 4 + w) * 65 + cg * 16 + lo] = v[cg] * inv;
  }
  __syncthreads();

  // waves 0,1 emit fp32 + frags (A-frag order: row = lo, ks = c*32+hi*8+j)
  if (w < 2) {
    const int c = w;
    float xs[8];
    #pragma unroll
    for (int j = 0; j < 8; ++j) xs[j] = t_lds[lo * 65 + c * 32 + hi * 8 + j];
    float* dp = zn + (size_t)(r0 + lo) * D_DIM + c * 32 + hi * 8;
    *(float4*)dp = make_float4(xs[0], xs[1], xs[2], xs[3]);
    *(float4*)(dp + 4) = make_float4(xs[4], xs[5], xs[6], xs[7]);
    bf16x8 H, M, L;
    limb3(xs, H, M, L);
    const int fb = (g * 2 + c) * 3;
    unsigned short* d0 = zn_sw + (size_t)(fb + 0) * 512 + l * 8;
    *(bf16x8*)d0 = H;
    *(bf16x8*)(d0 + 512) = M;
    *(bf16x8*)(d0 + 1024) = L;
  }
}

// ---------------------------------------------------------------------------
// K3 v10: 16x16x32 MFMA argmax, R10-proven 8-wave/4-group-step schedule,
// repartitioned: 32 y-slices x 16 groups (4 steps of 4 groups). Same 48KB
// LDS, same barrier:work ratio — but grid 1024 blocks now fills the LDS
// limit of 3 blocks/CU (R10's 512-block grid capped residency at 2), giving
// 6 waves/SIMD of cross-block barrier hiding. Per-row results go to a
// packed u64 best[] via atomicMax: key = (orderable_f32(dot) << 32) | ~idx
// — order-independent, lowest-index-on-tie (ties compare ~idx: larger =
// smaller idx). Replaces pval/pidx partials + k_out's 16-load merge.
__global__ __launch_bounds__(512) void k_argmax(
    const unsigned short* __restrict__ zn_sw,
    const unsigned short* __restrict__ cn_sw,
    unsigned long long* __restrict__ best) {
  __shared__ short smem[2 * 24 * 512];        // 2 bufs x 24 frags x 1KB
  const int tid = threadIdx.x;
  const int w = tid >> 6, l = tid & 63;       // w in 0..7
  const int lo = l & 15, hi = l >> 4;
  const int gA0 = (blockIdx.x * 8 + w) * 2;   // 0..510 (16-row groups)
  const int gB0 = blockIdx.y * 16;            // B group base (16 groups/slice)
  const bf16x8* Ab = (const bf16x8*)zn_sw;
  const char* Bbytes = (const char*)cn_sw;

  bf16x8 A0[2][3], A1[2][3];
  #pragma unroll
  for (int c = 0; c < 2; ++c)
    #pragma unroll
    for (int m = 0; m < 3; ++m) {
      A0[c][m] = Ab[(size_t)((gA0 * 2 + c) * 3 + m) * 64 + l];
      A1[c][m] = Ab[(size_t)(((gA0 + 1) * 2 + c) * 3 + m) * 64 + l];
    }

  float bv[8];
  int bi[8];
  #pragma unroll
  for (int i = 0; i < 8; ++i) { bv[i] = -1e30f; bi[i] = 0; }
  int cand = blockIdx.y * 256 + lo;

  // stage step s (4 groups = 24 contiguous 1KB frags) into buffer b;
  // wave w copies frags w*3 .. w*3+2 (8 waves x 3 = 24). Dest wave-uniform.
  #define STAGE(b, s)                                                         \
    {                                                                         \
      const int fb = (gB0 + (s) * 4) * 6 + w * 3;                             \
      _Pragma("unroll")                                                       \
      for (int i = 0; i < 3; ++i)                                             \
        gld_lds16(Bbytes + ((size_t)(fb + i) << 10) + (size_t)l * 16,         \
                  &smem[((b) * 24 + w * 3 + i) * 512]);                       \
    }

  #define MF(A_, B_, C_) __builtin_amdgcn_mfma_f32_16x16x32_bf16(A_, B_, C_, 0, 0, 0)

  // one 16-code group: B frags at local frag base LF (c*3+m layout)
  #define COMPUTE(LF)                                                         \
    {                                                                         \
      bf16x8 Bf[6];                                                           \
      _Pragma("unroll")                                                       \
      for (int i = 0; i < 6; ++i)                                             \
        Bf[i] = *(const bf16x8*)&smem[((LF) + i) * 512 + l * 8];              \
      f32x4 a0 = {0.f,0.f,0.f,0.f}, a1 = {0.f,0.f,0.f,0.f};                   \
      f32x4 a2 = {0.f,0.f,0.f,0.f}, a3 = {0.f,0.f,0.f,0.f};                   \
      a0 = MF(A0[0][0], Bf[0], a0); a1 = MF(A0[1][0], Bf[3], a1);             \
      a2 = MF(A1[0][0], Bf[0], a2); a3 = MF(A1[1][0], Bf[3], a3);             \
      a0 = MF(A0[0][0], Bf[1], a0); a1 = MF(A0[1][0], Bf[4], a1);             \
      a2 = MF(A1[0][0], Bf[1], a2); a3 = MF(A1[1][0], Bf[4], a3);             \
      a0 = MF(A0[0][1], Bf[0], a0); a1 = MF(A0[1][1], Bf[3], a1);             \
      a2 = MF(A1[0][1], Bf[0], a2); a3 = MF(A1[1][1], Bf[3], a3);             \
      a0 = MF(A0[0][0], Bf[2], a0); a1 = MF(A0[1][0], Bf[5], a1);             \
      a2 = MF(A1[0][0], Bf[2], a2); a3 = MF(A1[1][0], Bf[5], a3);             \
      a0 = MF(A0[0][2], Bf[0], a0); a1 = MF(A0[1][2], Bf[3], a1);             \
      a2 = MF(A1[0][2], Bf[0], a2); a3 = MF(A1[1][2], Bf[3], a3);             \
      a0 = MF(A0[0][1], Bf[1], a0); a1 = MF(A0[1][1], Bf[4], a1);             \
      a2 = MF(A1[0][1], Bf[1], a2); a3 = MF(A1[1][1], Bf[4], a3);             \
      _Pragma("unroll")                                                       \
      for (int r = 0; r < 4; ++r) {                                           \
        float d0 = a0[r] + a1[r];                                             \
        if (d0 > bv[r]) { bv[r] = d0; bi[r] = cand; }                         \
        float d1 = a2[r] + a3[r];                                             \
        if (d1 > bv[4 + r]) { bv[4 + r] = d1; bi[4 + r] = cand; }             \
      }                                                                       \
      cand += 16;                                                             \
    }

  STAGE(0, 0)
  __syncthreads();
  int cur = 0;
  for (int s = 0; s < 4; ++s) {
    if (s < 3) STAGE(cur ^ 1, s + 1)
    COMPUTE(cur * 24 + 0)
    COMPUTE(cur * 24 + 6)
    COMPUTE(cur * 24 + 12)
    COMPUTE(cur * 24 + 18)
    __syncthreads();      // drains stage loads; protects buffer reuse
    cur ^= 1;
  }
  #undef STAGE
  #undef COMPUTE
  #undef MF

  #pragma unroll
  for (int i = 0; i < 8; ++i) {
    float v = bv[i]; int ix = bi[i];
    #pragma unroll
    for (int m = 1; m < 16; m <<= 1) {
      float ov = __shfl_xor(v, m);
      int oi = __shfl_xor(ix, m);
      if (ov > v || (ov == v && oi < ix)) { v = ov; ix = oi; }
    }
    bv[i] = v; bi[i] = ix;
  }
  if (lo == 0) {
    const int base0 = gA0 * 16 + hi * 4;
    const int base1 = (gA0 + 1) * 16 + hi * 4;
    #pragma unroll
    for (int r = 0; r < 4; ++r) {
      unsigned k0 = __float_as_uint(bv[r]);
      k0 = (k0 & 0x80000000u) ? ~k0 : (k0 | 0x80000000u);
      atomicMax(&best[base0 + r],
                ((unsigned long long)k0 << 32) | (unsigned)(~bi[r]));
      unsigned k1 = __float_as_uint(bv[4 + r]);
      k1 = (k1 & 0x80000000u) ? ~k1 : (k1 | 0x80000000u);
      atomicMax(&best[base1 + r],
                ((unsigned long long)k1 << 32) | (unsigned)(~bi[4 + r]));
    }
  }
}

// ---------------------------------------------------------------------------
// K4 v7: fused gather + loss + out-GEMM. 512 blocks x 4 waves (R2-proven
// structure); winner index read as ONE u64 load from best[] (merge loop
// gone); loss finale folded in via one atomicAdd per block.
__global__ __launch_bounds__(256) void k_out(
    const float* __restrict__ cn, const float* __restrict__ zn,
    const unsigned long long* __restrict__ best,
    const unsigned short* __restrict__ w_out_sw,
    const float* __restrict__ b_out, float* __restrict__ out,
    float* __restrict__ idx_f, float* __restrict__ loss_f) {
  const int tid = threadIdx.x, w = tid >> 6, l = tid & 63;
  const int lo = l & 15, hi = l >> 4;
  const int r0 = blockIdx.x * 16;
  const int row = r0 + lo;

  const int ix = (int)(~(unsigned)best[row]);   // low 32 bits = ~idx
  if (w == 0 && hi == 0) idx_f[row] = (float)ix;

  // gather cn[ix], zn[row] in A-frag order; limb-split; loss partial
  bf16x8 A[2][3];
  float lp = 0.0f;
  #pragma unroll
  for (int c = 0; c < 2; ++c) {
    const float* cp = cn + (size_t)ix * D_DIM + c * 32 + hi * 8;
    const float* zp = zn + (size_t)row * D_DIM + c * 32 + hi * 8;
    float4 c0 = *(const float4*)cp, c1 = *(const float4*)(cp + 4);
    float4 z0 = *(const float4*)zp, z1 = *(const float4*)(zp + 4);
    float xs[8] = {c0.x, c0.y, c0.z, c0.w, c1.x, c1.y, c1.z, c1.w};
    float zs[8] = {z0.x, z0.y, z0.z, z0.w, z1.x, z1.y, z1.z, z1.w};
    limb3(xs, A[c][0], A[c][1], A[c][2]);
    #pragma unroll
    for (int j = 0; j < 8; ++j) { float d = xs[j] - zs[j]; lp += d * d; }
  }
  if (w == 0) {
    #pragma unroll
    for (int m = 1; m < 64; m <<= 1) lp += __shfl_xor(lp, m);
    if (l == 0) atomicAdd(loss_f, lp * (1.25f / (float)(N_ROWS * D_DIM)));
  }

  const bf16x8* Bptr = (const bf16x8*)w_out_sw;
  const int cgb = w * 8;                  // this wave's 8 column-groups
  bf16x8 Bu[6], Bv[6];
  #pragma unroll
  for (int i = 0; i < 6; ++i) Bu[i] = Bptr[((size_t)cgb * 6 + i) * 64 + l];

  #define OSTEP(BCUR, BNXT, CG)                                               \
    {                                                                         \
      _Pragma("unroll")                                                       \
      for (int i = 0; i < 6; ++i)                                             \
        BNXT[i] = Bptr[((size_t)((CG) + 1) * 6 + i) * 64 + l];                \
      f32x4 a0 = {0.f,0.f,0.f,0.f}, a1 = {0.f,0.f,0.f,0.f};                   \
      a0 = __builtin_amdgcn_mfma_f32_16x16x32_bf16(A[0][0], BCUR[0], a0, 0,0,0); \
      a1 = __builtin_amdgcn_mfma_f32_16x16x32_bf16(A[1][0], BCUR[3], a1, 0,0,0); \
      a0 = __builtin_amdgcn_mfma_f32_16x16x32_bf16(A[0][0], BCUR[1], a0, 0,0,0); \
      a1 = __builtin_amdgcn_mfma_f32_16x16x32_bf16(A[1][0], BCUR[4], a1, 0,0,0); \
      a0 = __builtin_amdgcn_mfma_f32_16x16x32_bf16(A[0][1], BCUR[0], a0, 0,0,0); \
      a1 = __builtin_amdgcn_mfma_f32_16x16x32_bf16(A[1][1], BCUR[3], a1, 0,0,0); \
      a0 = __builtin_amdgcn_mfma_f32_16x16x32_bf16(A[0][0], BCUR[2], a0, 0,0,0); \
      a1 = __builtin_amdgcn_mfma_f32_16x16x32_bf16(A[1][0], BCUR[5], a1, 0,0,0); \
      a0 = __builtin_amdgcn_mfma_f32_16x16x32_bf16(A[0][2], BCUR[0], a0, 0,0,0); \
      a1 = __builtin_amdgcn_mfma_f32_16x16x32_bf16(A[1][2], BCUR[3], a1, 0,0,0); \
      a0 = __builtin_amdgcn_mfma_f32_16x16x32_bf16(A[0][1], BCUR[1], a0, 0,0,0); \
      a1 = __builtin_amdgcn_mfma_f32_16x16x32_bf16(A[1][1], BCUR[4], a1, 0,0,0); \
      float bb = b_out[(CG) * 16 + lo];                                       \
      _Pragma("unroll")                                                       \
      for (int r = 0; r < 4; ++r)                                             \
        out[(size_t)(r0 + hi * 4 + r) * F_DIM + (CG) * 16 + lo] =             \
            a0[r] + a1[r] + bb;                                               \
    }

  for (int cg = cgb; cg < cgb + 8; cg += 2) {
    OSTEP(Bu, Bv, cg)          // w=3, cg=31's prefetch over-reads 6KB past
    OSTEP(Bv, Bu, cg + 1)      // wout_sw (lands in scratch - harmless)
  }
  #undef OSTEP
}

// ---------------------------------------------------------------------------
extern "C" void kernel_launch(void* const* d_in, const int* in_sizes, int n_in,
                              void* d_out, int out_size, void* d_ws, size_t ws_size,
                              hipStream_t stream) {
  const float* z        = (const float*)d_in[0];
  const float* W_in     = (const float*)d_in[1];
  const float* b_in     = (const float*)d_in[2];
  const float* codebook = (const float*)d_in[3];
  const float* W_out    = (const float*)d_in[4];
  const float* b_out    = (const float*)d_in[5];

  float* outp   = (float*)d_out;                      // Output 0: [8192 x 512]
  float* loss_f = outp + (size_t)N_ROWS * F_DIM;      // Output 1
  float* idx_f  = loss_f + 1;                         // Output 2

  // workspace layout (float units)
  float* wsf = (float*)d_ws;
  float* zn_ws = wsf;                                         // [0, 524288)
  float* cn_ws = wsf + 524288;                                // [524288, 1048576)
  unsigned short* zn_sw = (unsigned short*)(wsf + 1048576);   // 786432 f
  unsigned short* cn_sw = (unsigned short*)(wsf + 1835008);   // 786432 f, ends 2621440
  // 16 KB pad @ [2621440, 2625536) (legacy over-read pad, kept)
  unsigned short* win_sw  = (unsigned short*)(wsf + 2625536); // 49152 f
  unsigned short* wout_sw = (unsigned short*)(wsf + 2674688); // 49152 f, ends 2723840
  unsigned long long* best_ws = (unsigned long long*)(wsf + 2723840); // 8192 u64 = 16384 f
  // total 2740224 floats ~ 11.0 MB (shrank: pval/pidx partials removed)

  hipLaunchKernelGGL(k_prep, dim3(160), dim3(256), 0, stream,
                     W_in, W_out, codebook, win_sw, wout_sw, cn_ws, cn_sw,
                     loss_f, best_ws);
  hipLaunchKernelGGL(k_zn, dim3(512), dim3(256), 0, stream,
                     z, win_sw, b_in, zn_ws, zn_sw);
  hipLaunchKernelGGL(k_argmax, dim3(32, 32), dim3(512), 0, stream,
                     zn_sw, cn_sw, best_ws);
  hipLaunchKernelGGL(k_out, dim3(512), dim3(256), 0, stream,
                     cn_ws, zn_ws, best_ws, wout_sw, b_out,
                     outp, idx_f, loss_f);
}